// Round 14
// baseline (262.742 us; speedup 1.0000x reference)
//
#include <hip/hip_runtime.h>
#include <stdint.h>
#include <stddef.h>

typedef __attribute__((ext_vector_type(8))) short bf16x8;
typedef __attribute__((ext_vector_type(4))) float f32x4;
typedef __attribute__((ext_vector_type(16))) float f32x16;
typedef __attribute__((ext_vector_type(4))) unsigned int u32x4;

#define AS1 __attribute__((address_space(1)))
#define AS3 __attribute__((address_space(3)))

__device__ __forceinline__ void gll16(const void* g, void* l) {
  __builtin_amdgcn_global_load_lds((const AS1 unsigned int*)g, (AS3 unsigned int*)l, 16, 0, 0);
}

__device__ __forceinline__ uint16_t f2bf(float f) {
  uint32_t u = __builtin_bit_cast(uint32_t, f);
  u += 0x7fffu + ((u >> 16) & 1u);
  return (uint16_t)(u >> 16);
}
__device__ __forceinline__ float bf2f(uint16_t h) {
  uint32_t u = ((uint32_t)h) << 16;
  return __builtin_bit_cast(float, u);
}
// packed f32x2 -> bf16x2 in one instruction (RTNE, same as f2bf)
__device__ __forceinline__ uint32_t cvtpk(float lo, float hi) {
  uint32_t r;
  asm("v_cvt_pk_bf16_f32 %0, %1, %2" : "=v"(r) : "v"(lo), "v"(hi));
  return r;
}

#define BARRIER() do { asm volatile("" ::: "memory"); __builtin_amdgcn_s_barrier(); asm volatile("" ::: "memory"); } while (0)

// softmax scale * log2(e), folded into Q at the gemm_qkv epilogue
#define QSCALE (0.08838834764831845f * 1.4426950408889634f)

// ---------------------------------------------------------------- f32 -> bf16 (x, Wqkv, Wo) + RoPE table, one launch
__global__ void cvt_all(const float* __restrict__ x, const float* __restrict__ wqkv,
                        const float* __restrict__ wo,
                        uint16_t* __restrict__ xb, uint16_t* __restrict__ wqkvb,
                        uint16_t* __restrict__ wob,
                        float* __restrict__ cosT, float* __restrict__ sinT) {
  int b = blockIdx.x;
  if (b >= 12288) {   // rope table path: 512 blocks x 256 = 2048*64
    int idx = (b - 12288) * 256 + threadIdx.x;
    int s = idx >> 6, i = idx & 63;
    float invf = expf(-(float)i * (9.2103403719761836f / 64.0f));
    float f = (float)s * invf;
    cosT[idx] = cosf(f);
    sinT[idx] = sinf(f);
    return;
  }
  int i = b * 256 + threadIdx.x;  // n8 units
  const float* in; uint16_t* out; int off;
  if (i < 1048576)      { in = x;    out = xb;    off = i; }
  else if (i < 2621440) { in = wqkv; out = wqkvb; off = i - 1048576; }
  else                  { in = wo;   out = wob;   off = i - 2621440; }
  float4 a = reinterpret_cast<const float4*>(in)[2 * off];
  float4 c = reinterpret_cast<const float4*>(in)[2 * off + 1];
  union { uint16_t h[8]; u32x4 v; } u;
  u.h[0] = f2bf(a.x); u.h[1] = f2bf(a.y); u.h[2] = f2bf(a.z); u.h[3] = f2bf(a.w);
  u.h[4] = f2bf(c.x); u.h[5] = f2bf(c.y); u.h[6] = f2bf(c.z); u.h[7] = f2bf(c.w);
  reinterpret_cast<u32x4*>(out)[off] = u.v;
}

// ---------------------------------------------------------------- RoPE apply on K only (Q is roped in-register in attn)
__global__ void rope_apply_k(uint16_t* __restrict__ Kb,
                             const float* __restrict__ cosT, const float* __restrict__ sinT) {
  int id = blockIdx.x * blockDim.x + threadIdx.x;  // 32*2048*16 = 1048576
  int i = (id & 15) * 4;
  int s = (id >> 4) & 2047;
  int bh = id >> 15;
  size_t base = ((size_t)bh * 2048 + s) * 128;
  uint2 lo = *(const uint2*)&Kb[base + i];
  uint2 hi = *(const uint2*)&Kb[base + i + 64];
  float4 c  = *(const float4*)&cosT[(s << 6) + i];
  float4 sn = *(const float4*)&sinT[(s << 6) + i];
  float x00 = bf2f((uint16_t)(lo.x & 0xffff)), x01 = bf2f((uint16_t)(lo.x >> 16));
  float x02 = bf2f((uint16_t)(lo.y & 0xffff)), x03 = bf2f((uint16_t)(lo.y >> 16));
  float x10 = bf2f((uint16_t)(hi.x & 0xffff)), x11 = bf2f((uint16_t)(hi.x >> 16));
  float x12 = bf2f((uint16_t)(hi.y & 0xffff)), x13 = bf2f((uint16_t)(hi.y >> 16));
  uint2 olo = make_uint2(cvtpk(x00 * c.x - x10 * sn.x, x01 * c.y - x11 * sn.y),
                         cvtpk(x02 * c.z - x12 * sn.z, x03 * c.w - x13 * sn.w));
  uint2 ohi = make_uint2(cvtpk(x10 * c.x + x00 * sn.x, x11 * c.y + x01 * sn.y),
                         cvtpk(x12 * c.z + x02 * sn.z, x13 * c.w + x03 * sn.w));
  *(uint2*)&Kb[base + i]      = olo;
  *(uint2*)&Kb[base + i + 64] = ohi;
}

// ---------------------------------------------------------------- GEMM1: qkv = x @ Wqkv^T [256x192, 8-phase; Q pre-scaled]
__global__ __launch_bounds__(512, 2) void gemm_qkv(
    const uint16_t* __restrict__ A,   // [4096][2048]
    const uint16_t* __restrict__ B,   // [6144][2048]
    uint16_t* __restrict__ Qb, uint16_t* __restrict__ Kb, uint16_t* __restrict__ Vt) {
  extern __shared__ uint16_t L[];     // [buf2][A0 8192 | A1 8192 | B 12288]
  const int t = threadIdx.x, lane = t & 63, w = t >> 6;
  const int fr = lane & 15, fg = lane >> 4;
  const int wm = w >> 2, wn = w & 3;
  const int flat = blockIdx.y * 16 + blockIdx.x;
  const int swz = (flat & 7) * 64 + (flat >> 3);
  const int m0 = (swz & 15) * 256, n0 = (swz >> 4) * 192;

  f32x4 acc[8][3];
#pragma unroll
  for (int i = 0; i < 8; i++)
#pragma unroll
    for (int j = 0; j < 3; j++) acc[i][j] = (f32x4)(0.0f);

#define STA(kt, half)                                                             \
  do {                                                                            \
    if ((kt) < 32) {                                                              \
      int g0_ = m0 + (half) * 128;                                                \
      uint16_t* dst_ = &L[((kt) & 1) * 28672 + (half) * 8192];                    \
      _Pragma("unroll")                                                           \
      for (int j_ = 0; j_ < 2; ++j_) {                                            \
        int c_ = t + j_ * 512;                                                    \
        int row_ = c_ >> 3, cc_ = c_ & 7, scc_ = cc_ ^ (row_ & 7);                \
        gll16(&A[(size_t)(g0_ + row_) * 2048 + (kt) * 64 + scc_ * 8],             \
              &dst_[(c_ & ~63) * 8]);                                             \
      }                                                                           \
    }                                                                             \
  } while (0)

#define STB(kt)                                                                   \
  do {                                                                            \
    if ((kt) < 32) {                                                              \
      uint16_t* dst_ = &L[((kt) & 1) * 28672 + 16384];                            \
      _Pragma("unroll")                                                           \
      for (int j_ = 0; j_ < 3; ++j_) {                                            \
        int c_ = t + j_ * 512;                                                    \
        int row_ = c_ >> 3, cc_ = c_ & 7, scc_ = cc_ ^ (row_ & 7);                \
        gll16(&B[(size_t)(n0 + row_) * 2048 + (kt) * 64 + scc_ * 8],              \
              &dst_[(c_ & ~63) * 8]);                                             \
      }                                                                           \
    }                                                                             \
  } while (0)

  auto LDA4 = [&](bf16x8 (&af)[8], int buf, int mh) {
#pragma unroll
    for (int mi = 0; mi < 4; ++mi)
#pragma unroll
      for (int ks = 0; ks < 2; ++ks) {
        int lr = (mh * 4 + mi) * 16 + fr;
        int ck = (ks * 4 + fg) ^ (lr & 7);
        af[mi * 2 + ks] = *(const bf16x8*)&L[buf * 28672 + wm * 8192 + lr * 64 + ck * 8];
      }
  };
  auto LDB = [&](bf16x8* bfr, int buf, int ni0, int nn) {
#pragma unroll
    for (int ni = 0; ni < 2; ++ni) {
      if (ni >= nn) break;
#pragma unroll
      for (int ks = 0; ks < 2; ++ks) {
        int rn = wn * 48 + (ni0 + ni) * 16 + fr;
        int ck = (ks * 4 + fg) ^ (rn & 7);
        bfr[ni * 2 + ks] = *(const bf16x8*)&L[buf * 28672 + 16384 + rn * 64 + ck * 8];
      }
    }
  };
  auto MF = [&](bf16x8 (&af)[8], bf16x8* bfr, int mh, int ni0, int nn) {
    __builtin_amdgcn_s_setprio(1);
#pragma unroll
    for (int mi = 0; mi < 4; ++mi)
#pragma unroll
      for (int ni = 0; ni < 2; ++ni) {
        if (ni >= nn) break;
#pragma unroll
        for (int ks = 0; ks < 2; ++ks)
          acc[mh * 4 + mi][ni0 + ni] = __builtin_amdgcn_mfma_f32_16x16x32_bf16(
              af[mi * 2 + ks], bfr[ni * 2 + ks], acc[mh * 4 + mi][ni0 + ni], 0, 0, 0);
      }
    __builtin_amdgcn_s_setprio(0);
  };

  STA(0, 0); STA(0, 1); STB(0); STA(1, 0);
  asm volatile("s_waitcnt vmcnt(2)" ::: "memory");
  BARRIER();

  for (int tl = 0; tl < 32; ++tl) {
    const int buf = tl & 1;
    bf16x8 af[8], bA[4], bB[4];
    LDA4(af, buf, 0); LDB(bA, buf, 0, 2); STA(tl + 1, 1);
    BARRIER(); MF(af, bA, 0, 0, 2); BARRIER();
    LDB(bB, buf, 2, 1); STB(tl + 1);
    BARRIER(); MF(af, bB, 0, 2, 1); BARRIER();
    LDA4(af, buf, 1);
    BARRIER(); MF(af, bA, 1, 0, 2); BARRIER();
    STA(tl + 2, 0);
    BARRIER(); MF(af, bB, 1, 2, 1);
    if (tl < 30) asm volatile("s_waitcnt vmcnt(2)" ::: "memory");
    else         asm volatile("s_waitcnt vmcnt(0)" ::: "memory");
    BARRIER();
  }
#undef STA
#undef STB

#pragma unroll
  for (int mi = 0; mi < 8; ++mi) {
#pragma unroll
    for (int ni = 0; ni < 3; ++ni) {
      int ng = n0 + wn * 48 + ni * 16 + fr;
      int head = (ng >> 7) & 15, dd = ng & 127;
      if (ng < 4096) {
        uint16_t* dst = (ng < 2048) ? Qb : Kb;
        float sc = (ng < 2048) ? QSCALE : 1.0f;   // pre-scale Q (rope is linear)
#pragma unroll
        for (int r = 0; r < 4; r++) {
          int mg = m0 + wm * 128 + mi * 16 + fg * 4 + r;
          int b = mg >> 11, si = mg & 2047;
          dst[((size_t)(b * 16 + head) * 2048 + si) * 128 + dd] = f2bf(acc[mi][ni][r] * sc);
        }
      } else {
        uint2 pv = make_uint2(cvtpk(acc[mi][ni][0], acc[mi][ni][1]),
                              cvtpk(acc[mi][ni][2], acc[mi][ni][3]));
        int mg = m0 + wm * 128 + mi * 16 + fg * 4;
        int b = mg >> 11, si = mg & 2047;
        *(uint2*)&Vt[((size_t)(b * 16 + head) * 128 + dd) * 2048 + si] = pv;
      }
    }
  }
}

// ---------------------------------------------------------------- GEMM2: out = z @ Wo^T (f32 out) [unchanged 256x128 8-phase]
__global__ __launch_bounds__(512, 2) void gemm_out_k(
    const uint16_t* __restrict__ A,   // z [4096][2048] bf16
    const uint16_t* __restrict__ B,   // Wo [2048][2048] bf16
    float* __restrict__ C) {          // [4096][2048] f32
  extern __shared__ uint16_t L[];
  const int t = threadIdx.x, lane = t & 63, w = t >> 6;
  const int fr = lane & 15, fg = lane >> 4;
  const int wm = w >> 2, wn = w & 3;
  const int flat = blockIdx.y * 16 + blockIdx.x;
  const int swz = (flat & 7) * 32 + (flat >> 3);   // bijective, 256 % 8 == 0
  const int m0 = (swz & 15) * 256, n0 = (swz >> 4) * 128;

  f32x4 acc[8][2];
#pragma unroll
  for (int i = 0; i < 8; i++)
#pragma unroll
    for (int j = 0; j < 2; j++) acc[i][j] = (f32x4)(0.0f);

#define STA(kt, half)                                                             \
  do {                                                                            \
    if ((kt) < 32) {                                                              \
      int g0_ = m0 + (half) * 128;                                                \
      uint16_t* dst_ = &L[((kt) & 1) * 24576 + (half) * 8192];                    \
      _Pragma("unroll")                                                           \
      for (int j_ = 0; j_ < 2; ++j_) {                                            \
        int c_ = t + j_ * 512;                                                    \
        int row_ = c_ >> 3, cc_ = c_ & 7, scc_ = cc_ ^ (row_ & 7);                \
        gll16(&A[(size_t)(g0_ + row_) * 2048 + (kt) * 64 + scc_ * 8],             \
              &dst_[(c_ & ~63) * 8]);                                             \
      }                                                                           \
    }                                                                             \
  } while (0)

#define STB(kt)                                                                   \
  do {                                                                            \
    if ((kt) < 32) {                                                              \
      uint16_t* dst_ = &L[((kt) & 1) * 24576 + 16384];                            \
      _Pragma("unroll")                                                           \
      for (int j_ = 0; j_ < 2; ++j_) {                                            \
        int c_ = t + j_ * 512;                                                    \
        int row_ = c_ >> 3, cc_ = c_ & 7, scc_ = cc_ ^ (row_ & 7);                \
        gll16(&B[(size_t)(n0 + row_) * 2048 + (kt) * 64 + scc_ * 8],              \
              &dst_[(c_ & ~63) * 8]);                                             \
      }                                                                           \
    }                                                                             \
  } while (0)

  auto LDA4 = [&](bf16x8 (&af)[8], int buf, int mh) {
#pragma unroll
    for (int mi = 0; mi < 4; ++mi)
#pragma unroll
      for (int ks = 0; ks < 2; ++ks) {
        int lr = (mh * 4 + mi) * 16 + fr;
        int ck = (ks * 4 + fg) ^ (lr & 7);
        af[mi * 2 + ks] = *(const bf16x8*)&L[buf * 24576 + wm * 8192 + lr * 64 + ck * 8];
      }
  };
  auto LDB1 = [&](bf16x8 (&bfr)[2], int buf, int ni) {
#pragma unroll
    for (int ks = 0; ks < 2; ++ks) {
      int rn = wn * 32 + ni * 16 + fr;
      int ck = (ks * 4 + fg) ^ (rn & 7);
      bfr[ks] = *(const bf16x8*)&L[buf * 24576 + 16384 + rn * 64 + ck * 8];
    }
  };
  auto MF1 = [&](bf16x8 (&af)[8], bf16x8 (&bfr)[2], int mh, int ni) {
    __builtin_amdgcn_s_setprio(1);
#pragma unroll
    for (int mi = 0; mi < 4; ++mi)
#pragma unroll
      for (int ks = 0; ks < 2; ++ks)
        acc[mh * 4 + mi][ni] = __builtin_amdgcn_mfma_f32_16x16x32_bf16(
            af[mi * 2 + ks], bfr[ks], acc[mh * 4 + mi][ni], 0, 0, 0);
    __builtin_amdgcn_s_setprio(0);
  };

  STA(0, 0); STA(0, 1); STB(0); STA(1, 0);
  asm volatile("s_waitcnt vmcnt(2)" ::: "memory");
  BARRIER();

  for (int tl = 0; tl < 32; ++tl) {
    const int buf = tl & 1;
    bf16x8 af[8], bA[2], bB[2];
    LDA4(af, buf, 0); LDB1(bA, buf, 0); STA(tl + 1, 1);
    BARRIER(); MF1(af, bA, 0, 0); BARRIER();
    LDB1(bB, buf, 1); STB(tl + 1);
    BARRIER(); MF1(af, bB, 0, 1); BARRIER();
    LDA4(af, buf, 1);
    BARRIER(); MF1(af, bA, 1, 0); BARRIER();
    STA(tl + 2, 0);
    BARRIER(); MF1(af, bB, 1, 1);
    if (tl < 30) asm volatile("s_waitcnt vmcnt(2)" ::: "memory");
    else         asm volatile("s_waitcnt vmcnt(0)" ::: "memory");
    BARRIER();
  }
#undef STA
#undef STB

#pragma unroll
  for (int mi = 0; mi < 8; ++mi) {
#pragma unroll
    for (int ni = 0; ni < 2; ++ni) {
      int ng = n0 + wn * 32 + ni * 16 + fr;
#pragma unroll
      for (int r = 0; r < 4; r++) {
        int mg = m0 + wm * 128 + mi * 16 + fg * 4 + r;
        C[(size_t)mg * 2048 + ng] = acc[mi][ni][r];
      }
    }
  }
}

// ---------------------------------------------------------------- flash attention (causal), swapped 32x32 + in-reg softmax
// Round-14: split counted vmcnt per tile (T4). Steady state: entry = K(t) ready,
// V(t) in flight; issue K(t+1) then V(t+1); QK^T+softmax hides V(t) latency ->
// vmcnt(8)+barrier -> PV -> vmcnt(4)+barrier (K(t+1) ready, V(t+1) in flight).
// Outstanding never drains to 0 until the final tile.
__device__ __forceinline__ bf16x8 mk_pa(uint32_t p0, uint32_t p1, uint32_t p2, uint32_t p3, int hi) {
  uint32_t x0 = (uint32_t)__shfl_xor((int)p0, 32, 64);
  uint32_t x1 = (uint32_t)__shfl_xor((int)p1, 32, 64);
  uint32_t x2 = (uint32_t)__shfl_xor((int)p2, 32, 64);
  uint32_t x3 = (uint32_t)__shfl_xor((int)p3, 32, 64);
  u32x4 v;
  v[0] = hi ? x2 : p0;
  v[1] = hi ? x3 : p1;
  v[2] = hi ? p2 : x0;
  v[3] = hi ? p3 : x1;
  return __builtin_bit_cast(bf16x8, v);
}

__global__ __launch_bounds__(256, 2) void attn_kernel(
    const uint16_t* __restrict__ Qb, const uint16_t* __restrict__ Kb,
    const uint16_t* __restrict__ Vt, uint16_t* __restrict__ zb,
    const float* __restrict__ cosT, const float* __restrict__ sinT) {
  __shared__ uint16_t Ksh[2][64 * 128];   // [kv 64][d 128], 16B-chunk xor-swizzled by (kv&7)
  __shared__ uint16_t Vsh[2][128 * 64];   // [d 128][kv 64], 16B-chunk xor-swizzled by (d&7)

  const int t = threadIdx.x, lane = t & 63, w = t >> 6;
  const int l31 = lane & 31, hi = lane >> 5;
  const int bx = blockIdx.x, bh = blockIdx.y;
  const int qt = (bh & 16) ? (15 - bx) : bx;   // CU-pair balance: qt + qt' = 15
  const int q0 = qt * 128;
  const int qg = q0 + w * 32 + l31;
  const size_t hbase = (size_t)bh * 2048 * 128;

#define STAGE_K(kt, buf)                                                          \
  do {                                                                            \
    const uint16_t* Kg_ = Kb + hbase + (size_t)(kt) * 64 * 128;                   \
    _Pragma("unroll")                                                             \
    for (int i_ = 0; i_ < 4; i_++) {                                              \
      int c_ = t + i_ * 256;                                                      \
      int row_ = c_ >> 4, cc_ = c_ & 15, scc_ = cc_ ^ (row_ & 7);                 \
      gll16(&Kg_[row_ * 128 + scc_ * 8], &Ksh[buf][(c_ & ~63) * 8]);              \
    }                                                                             \
  } while (0)

#define STAGE_V(kt, buf)                                                          \
  do {                                                                            \
    const uint16_t* Vg_ = Vt + hbase + (size_t)(kt) * 64;                         \
    _Pragma("unroll")                                                             \
    for (int i_ = 0; i_ < 4; i_++) {                                              \
      int c_ = t + i_ * 256;                                                      \
      int r_ = c_ >> 3, cc_ = c_ & 7, scc_ = cc_ ^ (r_ & 7);                      \
      gll16(&Vg_[(size_t)r_ * 2048 + scc_ * 8], &Vsh[buf][(c_ & ~63) * 8]);       \
    }                                                                             \
  } while (0)

  // ---- load Q frags and apply RoPE in-register (Q already carries QSCALE)
  bf16x8 qf[8];
#pragma unroll
  for (int dc = 0; dc < 8; ++dc)
    qf[dc] = *(const bf16x8*)&Qb[hbase + (size_t)qg * 128 + dc * 16 + hi * 8];
#pragma unroll
  for (int dc = 0; dc < 4; ++dc) {
    int d0 = dc * 16 + hi * 8;
    float4 c0 = *(const float4*)&cosT[(qg << 6) + d0];
    float4 c1 = *(const float4*)&cosT[(qg << 6) + d0 + 4];
    float4 n0 = *(const float4*)&sinT[(qg << 6) + d0];
    float4 n1 = *(const float4*)&sinT[(qg << 6) + d0 + 4];
    float cs[8] = {c0.x, c0.y, c0.z, c0.w, c1.x, c1.y, c1.z, c1.w};
    float sn[8] = {n0.x, n0.y, n0.z, n0.w, n1.x, n1.y, n1.z, n1.w};
    uint32_t lo2[4], hi2[4];
#pragma unroll
    for (int j = 0; j < 4; ++j) {
      float xl0 = bf2f((uint16_t)qf[dc][2 * j]),     xh0 = bf2f((uint16_t)qf[dc + 4][2 * j]);
      float xl1 = bf2f((uint16_t)qf[dc][2 * j + 1]), xh1 = bf2f((uint16_t)qf[dc + 4][2 * j + 1]);
      lo2[j] = cvtpk(xl0 * cs[2 * j] - xh0 * sn[2 * j], xl1 * cs[2 * j + 1] - xh1 * sn[2 * j + 1]);
      hi2[j] = cvtpk(xh0 * cs[2 * j] + xl0 * sn[2 * j], xh1 * cs[2 * j + 1] + xl1 * sn[2 * j + 1]);
    }
    { u32x4 v = {lo2[0], lo2[1], lo2[2], lo2[3]}; qf[dc]     = __builtin_bit_cast(bf16x8, v); }
    { u32x4 v = {hi2[0], hi2[1], hi2[2], hi2[3]}; qf[dc + 4] = __builtin_bit_cast(bf16x8, v); }
  }

  f32x16 oacc[4];
#pragma unroll
  for (int i = 0; i < 4; i++) oacc[i] = (f32x16)(0.0f);
  float mrow = -1e30f, lrow = 0.0f;

  const int ktiles = 2 * qt + 2;
  // prologue: K(0) then V(0); wait K landed (V stays in flight)
  STAGE_K(0, 0);
  STAGE_V(0, 0);
  asm volatile("s_waitcnt vmcnt(4)" ::: "memory");
  BARRIER();

  for (int kt = 0; kt < ktiles; ++kt) {
    const int cur = kt & 1;
    const bool more = (kt + 1 < ktiles);
    if (more) { STAGE_K(kt + 1, cur ^ 1); STAGE_V(kt + 1, cur ^ 1); }

    const int kv_base = kt * 64;
    const bool work = (kv_base <= q0 + w * 32 + 31);
    float ps = 0.0f;
    bf16x8 pa[4];

    if (work) {
      f32x16 s0 = (f32x16)(0.0f), s1 = (f32x16)(0.0f);
      __builtin_amdgcn_s_setprio(1);
#pragma unroll
      for (int dc = 0; dc < 8; ++dc) {
        int ch = dc * 2 + hi;
        bf16x8 k0 = *(const bf16x8*)&Ksh[cur][l31 * 128 + ((ch ^ (l31 & 7)) * 8)];
        bf16x8 k1 = *(const bf16x8*)&Ksh[cur][(32 + l31) * 128 + ((ch ^ (l31 & 7)) * 8)];
        s0 = __builtin_amdgcn_mfma_f32_32x32x16_bf16(k0, qf[dc], s0, 0, 0, 0);
        s1 = __builtin_amdgcn_mfma_f32_32x32x16_bf16(k1, qf[dc], s1, 0, 0, 0);
      }
      __builtin_amdgcn_s_setprio(0);

      // mask in place only on diagonal tiles (Q already carries scale*log2e)
      if (kv_base + 63 > q0 + w * 32) {
#pragma unroll
        for (int reg = 0; reg < 16; ++reg) {
          int koff = (reg & 3) + 8 * (reg >> 2) + 4 * hi;
          if (kv_base + koff > qg) s0[reg] = -1e30f;
          if (kv_base + 32 + koff > qg) s1[reg] = -1e30f;
        }
      }

      // ---- row max: tree
      float m8[8];
#pragma unroll
      for (int i = 0; i < 8; ++i)
        m8[i] = fmaxf(fmaxf(s0[i], s0[i + 8]), fmaxf(s1[i], s1[i + 8]));
      float pmax = fmaxf(fmaxf(fmaxf(m8[0], m8[4]), fmaxf(m8[1], m8[5])),
                         fmaxf(fmaxf(m8[2], m8[6]), fmaxf(m8[3], m8[7])));
      pmax = fmaxf(pmax, __shfl_xor(pmax, 32, 64));

      bool defer = __all(pmax <= mrow + 8.0f);
      if (!defer) {
        float mnew = fmaxf(mrow, pmax);
        float al = exp2f(mrow - mnew);
        lrow *= al;
#pragma unroll
        for (int reg = 0; reg < 16; ++reg) {
          int src = (reg & 3) + 8 * (reg >> 2) + 4 * hi;
          float ar = __shfl(al, src, 64);
#pragma unroll
          for (int n = 0; n < 4; ++n) oacc[n][reg] *= ar;
        }
        mrow = mnew;
      }

      // ---- P = exp2(s - mrow): cvt_pk pack + 4-way partial sums
      float ps0 = 0.0f, ps1 = 0.0f, ps2 = 0.0f, ps3 = 0.0f;
      uint32_t pk0[8], pk1[8];
#pragma unroll
      for (int i = 0; i < 8; ++i) {
        float a = exp2f(s0[2 * i] - mrow), b = exp2f(s0[2 * i + 1] - mrow);
        ps0 += a; ps1 += b;
        pk0[i] = cvtpk(a, b);
        float c = exp2f(s1[2 * i] - mrow), d = exp2f(s1[2 * i + 1] - mrow);
        ps2 += c; ps3 += d;
        pk1[i] = cvtpk(c, d);
      }
      ps = (ps0 + ps1) + (ps2 + ps3);
      ps += __shfl_xor(ps, 32, 64);
      lrow += ps;

      pa[0] = mk_pa(pk0[0], pk0[1], pk0[2], pk0[3], hi);
      pa[1] = mk_pa(pk0[4], pk0[5], pk0[6], pk0[7], hi);
      pa[2] = mk_pa(pk1[0], pk1[1], pk1[2], pk1[3], hi);
      pa[3] = mk_pa(pk1[4], pk1[5], pk1[6], pk1[7], hi);
    }

    // V(kt) landed (the 8 newest = K(kt+1),V(kt+1) stay in flight; 0 on last tile)
    if (more) asm volatile("s_waitcnt vmcnt(8)" ::: "memory");
    else      asm volatile("s_waitcnt vmcnt(0)" ::: "memory");
    BARRIER();

    if (work) {
      __builtin_amdgcn_s_setprio(1);
#pragma unroll
      for (int ksl = 0; ksl < 4; ++ksl) {
        int ch = ksl * 2 + hi;
#pragma unroll
        for (int n = 0; n < 4; ++n) {
          int d = n * 32 + l31;
          bf16x8 vf = *(const bf16x8*)&Vsh[cur][d * 64 + ((ch ^ (d & 7)) * 8)];
          oacc[n] = __builtin_amdgcn_mfma_f32_32x32x16_bf16(pa[ksl], vf, oacc[n], 0, 0, 0);
        }
      }
      __builtin_amdgcn_s_setprio(0);
    }

    if (more) {
      // K(kt+1) landed; V(kt+1) (newest 4) stays in flight across the barrier
      asm volatile("s_waitcnt vmcnt(4)" ::: "memory");
      BARRIER();
    }
  }
#undef STAGE_K
#undef STAGE_V

  const int b = bh >> 4, h = bh & 15;
  const float linv_own = 1.0f / lrow;   // one divide per lane (its own q-row)
#pragma unroll
  for (int reg = 0; reg < 16; ++reg) {
    int rloc = (reg & 3) + 8 * (reg >> 2) + 4 * hi;
    float linv = __shfl(linv_own, rloc, 64);
    int rowg = q0 + w * 32 + rloc;
    size_t base = ((size_t)b * 2048 + rowg) * 2048 + h * 128 + l31;
#pragma unroll
    for (int n = 0; n < 4; ++n)
      zb[base + n * 32] = f2bf(oacc[n][reg] * linv);
  }
}

// ---------------------------------------------------------------- launch
extern "C" void kernel_launch(void* const* d_in, const int* in_sizes, int n_in,
                              void* d_out, int out_size, void* d_ws, size_t ws_size,
                              hipStream_t stream) {
  const float* x    = (const float*)d_in[0];
  const float* Wqkv = (const float*)d_in[1];
  const float* Wo   = (const float*)d_in[2];
  float* out = (float*)d_out;
  char* ws = (char*)d_ws;

  uint16_t* Qb    = (uint16_t*)(ws + 0);            // 16 MB
  uint16_t* Kb    = (uint16_t*)(ws + 16777216);     // 16 MB
  uint16_t* Vt    = (uint16_t*)(ws + 33554432);     // 16 MB  [b,h,128,2048]
  uint16_t* xb    = (uint16_t*)(ws + 50331648);     // 16 MB (dead after gemm_qkv)
  uint16_t* zb    = (uint16_t*)(ws + 50331648);     // alias xb
  uint16_t* wqkvb = (uint16_t*)(ws + 67108864);     // 24 MB
  uint16_t* wob   = (uint16_t*)(ws + 92274688);     //  8 MB
  float*    cosT  = (float*)   (ws + 100663296);
  float*    sinT  = (float*)   (ws + 101187584);

  cvt_all<<<12800, 256, 0, stream>>>(x, Wqkv, Wo, xb, wqkvb, wob, cosT, sinT);

  gemm_qkv<<<dim3(16, 32), 512, 114688, stream>>>(xb, wqkvb, Qb, Kb, Vt);

  rope_apply_k<<<4096, 256, 0, stream>>>(Kb, cosT, sinT);

  attn_kernel<<<dim3(16, 32), 256, 0, stream>>>(Qb, Kb, Vt, zb, cosT, sinT);

  gemm_out_k<<<dim3(16, 16), 512, 98304, stream>>>(zb, wob, out);
}

// Round 15
// 260.828 us; speedup vs baseline: 1.0073x; 1.0073x over previous
//
#include <hip/hip_runtime.h>
#include <stdint.h>
#include <stddef.h>

typedef __attribute__((ext_vector_type(8))) short bf16x8;
typedef __attribute__((ext_vector_type(4))) float f32x4;
typedef __attribute__((ext_vector_type(16))) float f32x16;
typedef __attribute__((ext_vector_type(4))) unsigned int u32x4;

#define AS1 __attribute__((address_space(1)))
#define AS3 __attribute__((address_space(3)))

__device__ __forceinline__ void gll16(const void* g, void* l) {
  __builtin_amdgcn_global_load_lds((const AS1 unsigned int*)g, (AS3 unsigned int*)l, 16, 0, 0);
}

__device__ __forceinline__ uint16_t f2bf(float f) {
  uint32_t u = __builtin_bit_cast(uint32_t, f);
  u += 0x7fffu + ((u >> 16) & 1u);
  return (uint16_t)(u >> 16);
}
__device__ __forceinline__ float bf2f(uint16_t h) {
  uint32_t u = ((uint32_t)h) << 16;
  return __builtin_bit_cast(float, u);
}
// packed f32x2 -> bf16x2 in one instruction (RTNE, same as f2bf)
__device__ __forceinline__ uint32_t cvtpk(float lo, float hi) {
  uint32_t r;
  asm("v_cvt_pk_bf16_f32 %0, %1, %2" : "=v"(r) : "v"(lo), "v"(hi));
  return r;
}

#define BARRIER() do { asm volatile("" ::: "memory"); __builtin_amdgcn_s_barrier(); asm volatile("" ::: "memory"); } while (0)

// softmax scale * log2(e), folded into Q at the gemm_qkv epilogue
#define QSCALE (0.08838834764831845f * 1.4426950408889634f)

// ---------------------------------------------------------------- f32 -> bf16 (x, Wqkv, Wo) + RoPE table, one launch
__global__ void cvt_all(const float* __restrict__ x, const float* __restrict__ wqkv,
                        const float* __restrict__ wo,
                        uint16_t* __restrict__ xb, uint16_t* __restrict__ wqkvb,
                        uint16_t* __restrict__ wob,
                        float* __restrict__ cosT, float* __restrict__ sinT) {
  int b = blockIdx.x;
  if (b >= 12288) {   // rope table path: 512 blocks x 256 = 2048*64
    int idx = (b - 12288) * 256 + threadIdx.x;
    int s = idx >> 6, i = idx & 63;
    float invf = expf(-(float)i * (9.2103403719761836f / 64.0f));
    float f = (float)s * invf;
    cosT[idx] = cosf(f);
    sinT[idx] = sinf(f);
    return;
  }
  int i = b * 256 + threadIdx.x;  // n8 units
  const float* in; uint16_t* out; int off;
  if (i < 1048576)      { in = x;    out = xb;    off = i; }
  else if (i < 2621440) { in = wqkv; out = wqkvb; off = i - 1048576; }
  else                  { in = wo;   out = wob;   off = i - 2621440; }
  float4 a = reinterpret_cast<const float4*>(in)[2 * off];
  float4 c = reinterpret_cast<const float4*>(in)[2 * off + 1];
  union { uint16_t h[8]; u32x4 v; } u;
  u.h[0] = f2bf(a.x); u.h[1] = f2bf(a.y); u.h[2] = f2bf(a.z); u.h[3] = f2bf(a.w);
  u.h[4] = f2bf(c.x); u.h[5] = f2bf(c.y); u.h[6] = f2bf(c.z); u.h[7] = f2bf(c.w);
  reinterpret_cast<u32x4*>(out)[off] = u.v;
}

// ---------------------------------------------------------------- RoPE apply on K only (Q is roped in-register in attn)
__global__ void rope_apply_k(uint16_t* __restrict__ Kb,
                             const float* __restrict__ cosT, const float* __restrict__ sinT) {
  int id = blockIdx.x * blockDim.x + threadIdx.x;  // 32*2048*16 = 1048576
  int i = (id & 15) * 4;
  int s = (id >> 4) & 2047;
  int bh = id >> 15;
  size_t base = ((size_t)bh * 2048 + s) * 128;
  uint2 lo = *(const uint2*)&Kb[base + i];
  uint2 hi = *(const uint2*)&Kb[base + i + 64];
  float4 c  = *(const float4*)&cosT[(s << 6) + i];
  float4 sn = *(const float4*)&sinT[(s << 6) + i];
  float x00 = bf2f((uint16_t)(lo.x & 0xffff)), x01 = bf2f((uint16_t)(lo.x >> 16));
  float x02 = bf2f((uint16_t)(lo.y & 0xffff)), x03 = bf2f((uint16_t)(lo.y >> 16));
  float x10 = bf2f((uint16_t)(hi.x & 0xffff)), x11 = bf2f((uint16_t)(hi.x >> 16));
  float x12 = bf2f((uint16_t)(hi.y & 0xffff)), x13 = bf2f((uint16_t)(hi.y >> 16));
  uint2 olo = make_uint2(cvtpk(x00 * c.x - x10 * sn.x, x01 * c.y - x11 * sn.y),
                         cvtpk(x02 * c.z - x12 * sn.z, x03 * c.w - x13 * sn.w));
  uint2 ohi = make_uint2(cvtpk(x10 * c.x + x00 * sn.x, x11 * c.y + x01 * sn.y),
                         cvtpk(x12 * c.z + x02 * sn.z, x13 * c.w + x03 * sn.w));
  *(uint2*)&Kb[base + i]      = olo;
  *(uint2*)&Kb[base + i + 64] = ohi;
}

// ---------------------------------------------------------------- GEMM1: qkv = x @ Wqkv^T
// Round-15: 256x192 tile, BK=64, 4M x 2N wave arrangement (per-wave 64x96,
// acc[4][6]). LDS reads/K-tile: A 64KB + B 96KB = 160 KB (was 176 with 2Mx4N).
// 3 phases x 2 barriers + boundary = 7 barriers/tile (was 9).
// Stage slots: q0: A1(t+1), q1: B(t+1), q2: A0(t+2). A(cur) is dead after the
// q0 barrier (all A-frags read at q0), so A0(t+2)->cur buf at q2 is safe.
// Boundary vmcnt(2) keeps A0(t+2)'s 2 insts in flight.
__global__ __launch_bounds__(512, 2) void gemm_qkv(
    const uint16_t* __restrict__ A,   // [4096][2048]
    const uint16_t* __restrict__ B,   // [6144][2048]
    uint16_t* __restrict__ Qb, uint16_t* __restrict__ Kb, uint16_t* __restrict__ Vt) {
  extern __shared__ uint16_t L[];     // [buf2][A0 8192 | A1 8192 | B 12288]
  const int t = threadIdx.x, lane = t & 63, w = t >> 6;
  const int fr = lane & 15, fg = lane >> 4;
  const int wm = w >> 1, wn = w & 1;   // 4 M-groups x 2 N-groups
  const int flat = blockIdx.y * 16 + blockIdx.x;
  const int swz = (flat & 7) * 64 + (flat >> 3);
  const int m0 = (swz & 15) * 256, n0 = (swz >> 4) * 192;

  f32x4 acc[4][6];
#pragma unroll
  for (int i = 0; i < 4; i++)
#pragma unroll
    for (int j = 0; j < 6; j++) acc[i][j] = (f32x4)(0.0f);

#define STA(kt, half)                                                             \
  do {                                                                            \
    if ((kt) < 32) {                                                              \
      int g0_ = m0 + (half) * 128;                                                \
      uint16_t* dst_ = &L[((kt) & 1) * 28672 + (half) * 8192];                    \
      _Pragma("unroll")                                                           \
      for (int j_ = 0; j_ < 2; ++j_) {                                            \
        int c_ = t + j_ * 512;                                                    \
        int row_ = c_ >> 3, cc_ = c_ & 7, scc_ = cc_ ^ (row_ & 7);                \
        gll16(&A[(size_t)(g0_ + row_) * 2048 + (kt) * 64 + scc_ * 8],             \
              &dst_[(c_ & ~63) * 8]);                                             \
      }                                                                           \
    }                                                                             \
  } while (0)

#define STB(kt)                                                                   \
  do {                                                                            \
    if ((kt) < 32) {                                                              \
      uint16_t* dst_ = &L[((kt) & 1) * 28672 + 16384];                            \
      _Pragma("unroll")                                                           \
      for (int j_ = 0; j_ < 3; ++j_) {                                            \
        int c_ = t + j_ * 512;                                                    \
        int row_ = c_ >> 3, cc_ = c_ & 7, scc_ = cc_ ^ (row_ & 7);                \
        gll16(&B[(size_t)(n0 + row_) * 2048 + (kt) * 64 + scc_ * 8],              \
              &dst_[(c_ & ~63) * 8]);                                             \
      }                                                                           \
    }                                                                             \
  } while (0)

  // all 8 A-frags of the wave's 64-row panel (4 mi x 2 ks)
  auto LDA8 = [&](bf16x8 (&af)[8], int buf) {
#pragma unroll
    for (int mi = 0; mi < 4; ++mi)
#pragma unroll
      for (int ks = 0; ks < 2; ++ks) {
        int lr = wm * 64 + mi * 16 + fr;          // 0..255
        int half = lr >> 7, ll = lr & 127;
        int ck = (ks * 4 + fg) ^ (ll & 7);
        af[mi * 2 + ks] = *(const bf16x8*)&L[buf * 28672 + half * 8192 + ll * 64 + ck * 8];
      }
  };
  auto LDB2 = [&](bf16x8 (&bfr)[4], int buf, int ni0) {  // 2 ni x 2 ks
#pragma unroll
    for (int ni = 0; ni < 2; ++ni)
#pragma unroll
      for (int ks = 0; ks < 2; ++ks) {
        int rn = wn * 96 + (ni0 + ni) * 16 + fr;  // 0..191
        int ck = (ks * 4 + fg) ^ (rn & 7);
        bfr[ni * 2 + ks] = *(const bf16x8*)&L[buf * 28672 + 16384 + rn * 64 + ck * 8];
      }
  };
  auto MF2 = [&](bf16x8 (&af)[8], bf16x8 (&bfr)[4], int ni0) {
    __builtin_amdgcn_s_setprio(1);
#pragma unroll
    for (int mi = 0; mi < 4; ++mi)
#pragma unroll
      for (int ni = 0; ni < 2; ++ni)
#pragma unroll
        for (int ks = 0; ks < 2; ++ks)
          acc[mi][ni0 + ni] = __builtin_amdgcn_mfma_f32_16x16x32_bf16(
              af[mi * 2 + ks], bfr[ni * 2 + ks], acc[mi][ni0 + ni], 0, 0, 0);
    __builtin_amdgcn_s_setprio(0);
  };

  // prologue: tile0 (A0,A1,B) + A0(1); keep A0(1)'s 2 insts in flight
  STA(0, 0); STA(0, 1); STB(0); STA(1, 0);
  asm volatile("s_waitcnt vmcnt(2)" ::: "memory");
  BARRIER();

  for (int tl = 0; tl < 32; ++tl) {
    const int buf = tl & 1;
    bf16x8 af[8], b01[4], b23[4], b45[4];
    // q0: all A-frags + B(ni0,1); stage A1(t+1)
    LDA8(af, buf); LDB2(b01, buf, 0); STA(tl + 1, 1);
    BARRIER(); MF2(af, b01, 0); BARRIER();
    // q1: B(ni2,3); stage B(t+1)
    LDB2(b23, buf, 2); STB(tl + 1);
    BARRIER(); MF2(af, b23, 2); BARRIER();
    // q2: B(ni4,5); stage A0(t+2) (cur A dead since q0 barrier)
    LDB2(b45, buf, 4); STA(tl + 2, 0);
    BARRIER(); MF2(af, b45, 4);
    // boundary: t+1 fully landed, keep A0(t+2) in flight
    if (tl < 30) asm volatile("s_waitcnt vmcnt(2)" ::: "memory");
    else         asm volatile("s_waitcnt vmcnt(0)" ::: "memory");
    BARRIER();
  }
#undef STA
#undef STB

  // epilogue: Q/K scatter (Q pre-scaled), V transposed packed 8B stores
#pragma unroll
  for (int mi = 0; mi < 4; ++mi) {
#pragma unroll
    for (int ni = 0; ni < 6; ++ni) {
      int ng = n0 + wn * 96 + ni * 16 + fr;
      int head = (ng >> 7) & 15, dd = ng & 127;
      if (ng < 4096) {
        uint16_t* dst = (ng < 2048) ? Qb : Kb;
        float sc = (ng < 2048) ? QSCALE : 1.0f;
#pragma unroll
        for (int r = 0; r < 4; r++) {
          int mg = m0 + wm * 64 + mi * 16 + fg * 4 + r;
          int b = mg >> 11, si = mg & 2047;
          dst[((size_t)(b * 16 + head) * 2048 + si) * 128 + dd] = f2bf(acc[mi][ni][r] * sc);
        }
      } else {
        uint2 pv = make_uint2(cvtpk(acc[mi][ni][0], acc[mi][ni][1]),
                              cvtpk(acc[mi][ni][2], acc[mi][ni][3]));
        int mg = m0 + wm * 64 + mi * 16 + fg * 4;
        int b = mg >> 11, si = mg & 2047;
        *(uint2*)&Vt[((size_t)(b * 16 + head) * 128 + dd) * 2048 + si] = pv;
      }
    }
  }
}

// ---------------------------------------------------------------- GEMM2: out = z @ Wo^T (f32 out) [unchanged 256x128 8-phase]
__global__ __launch_bounds__(512, 2) void gemm_out_k(
    const uint16_t* __restrict__ A,   // z [4096][2048] bf16
    const uint16_t* __restrict__ B,   // Wo [2048][2048] bf16
    float* __restrict__ C) {          // [4096][2048] f32
  extern __shared__ uint16_t L[];
  const int t = threadIdx.x, lane = t & 63, w = t >> 6;
  const int fr = lane & 15, fg = lane >> 4;
  const int wm = w >> 2, wn = w & 3;
  const int flat = blockIdx.y * 16 + blockIdx.x;
  const int swz = (flat & 7) * 32 + (flat >> 3);   // bijective, 256 % 8 == 0
  const int m0 = (swz & 15) * 256, n0 = (swz >> 4) * 128;

  f32x4 acc[8][2];
#pragma unroll
  for (int i = 0; i < 8; i++)
#pragma unroll
    for (int j = 0; j < 2; j++) acc[i][j] = (f32x4)(0.0f);

#define STA(kt, half)                                                             \
  do {                                                                            \
    if ((kt) < 32) {                                                              \
      int g0_ = m0 + (half) * 128;                                                \
      uint16_t* dst_ = &L[((kt) & 1) * 24576 + (half) * 8192];                    \
      _Pragma("unroll")                                                           \
      for (int j_ = 0; j_ < 2; ++j_) {                                            \
        int c_ = t + j_ * 512;                                                    \
        int row_ = c_ >> 3, cc_ = c_ & 7, scc_ = cc_ ^ (row_ & 7);                \
        gll16(&A[(size_t)(g0_ + row_) * 2048 + (kt) * 64 + scc_ * 8],             \
              &dst_[(c_ & ~63) * 8]);                                             \
      }                                                                           \
    }                                                                             \
  } while (0)

#define STB(kt)                                                                   \
  do {                                                                            \
    if ((kt) < 32) {                                                              \
      uint16_t* dst_ = &L[((kt) & 1) * 24576 + 16384];                            \
      _Pragma("unroll")                                                           \
      for (int j_ = 0; j_ < 2; ++j_) {                                            \
        int c_ = t + j_ * 512;                                                    \
        int row_ = c_ >> 3, cc_ = c_ & 7, scc_ = cc_ ^ (row_ & 7);                \
        gll16(&B[(size_t)(n0 + row_) * 2048 + (kt) * 64 + scc_ * 8],              \
              &dst_[(c_ & ~63) * 8]);                                             \
      }                                                                           \
    }                                                                             \
  } while (0)

  auto LDA4 = [&](bf16x8 (&af)[8], int buf, int mh) {
#pragma unroll
    for (int mi = 0; mi < 4; ++mi)
#pragma unroll
      for (int ks = 0; ks < 2; ++ks) {
        int lr = (mh * 4 + mi) * 16 + fr;
        int ck = (ks * 4 + fg) ^ (lr & 7);
        af[mi * 2 + ks] = *(const bf16x8*)&L[buf * 24576 + wm * 8192 + lr * 64 + ck * 8];
      }
  };
  auto LDB1 = [&](bf16x8 (&bfr)[2], int buf, int ni) {
#pragma unroll
    for (int ks = 0; ks < 2; ++ks) {
      int rn = wn * 32 + ni * 16 + fr;
      int ck = (ks * 4 + fg) ^ (rn & 7);
      bfr[ks] = *(const bf16x8*)&L[buf * 24576 + 16384 + rn * 64 + ck * 8];
    }
  };
  auto MF1 = [&](bf16x8 (&af)[8], bf16x8 (&bfr)[2], int mh, int ni) {
    __builtin_amdgcn_s_setprio(1);
#pragma unroll
    for (int mi = 0; mi < 4; ++mi)
#pragma unroll
      for (int ks = 0; ks < 2; ++ks)
        acc[mh * 4 + mi][ni] = __builtin_amdgcn_mfma_f32_16x16x32_bf16(
            af[mi * 2 + ks], bfr[ks], acc[mh * 4 + mi][ni], 0, 0, 0);
    __builtin_amdgcn_s_setprio(0);
  };

  STA(0, 0); STA(0, 1); STB(0); STA(1, 0);
  asm volatile("s_waitcnt vmcnt(2)" ::: "memory");
  BARRIER();

  for (int tl = 0; tl < 32; ++tl) {
    const int buf = tl & 1;
    bf16x8 af[8], bA[2], bB[2];
    LDA4(af, buf, 0); LDB1(bA, buf, 0); STA(tl + 1, 1);
    BARRIER(); MF1(af, bA, 0, 0); BARRIER();
    LDB1(bB, buf, 1); STB(tl + 1);
    BARRIER(); MF1(af, bB, 0, 1); BARRIER();
    LDA4(af, buf, 1);
    BARRIER(); MF1(af, bA, 1, 0); BARRIER();
    STA(tl + 2, 0);
    BARRIER(); MF1(af, bB, 1, 1);
    if (tl < 30) asm volatile("s_waitcnt vmcnt(2)" ::: "memory");
    else         asm volatile("s_waitcnt vmcnt(0)" ::: "memory");
    BARRIER();
  }
#undef STA
#undef STB

#pragma unroll
  for (int mi = 0; mi < 8; ++mi) {
#pragma unroll
    for (int ni = 0; ni < 2; ++ni) {
      int ng = n0 + wn * 32 + ni * 16 + fr;
#pragma unroll
      for (int r = 0; r < 4; r++) {
        int mg = m0 + wm * 128 + mi * 16 + fg * 4 + r;
        C[(size_t)mg * 2048 + ng] = acc[mi][ni][r];
      }
    }
  }
}

// ---------------------------------------------------------------- flash attention (causal) [reverted to round-13 schedule]
__device__ __forceinline__ bf16x8 mk_pa(uint32_t p0, uint32_t p1, uint32_t p2, uint32_t p3, int hi) {
  uint32_t x0 = (uint32_t)__shfl_xor((int)p0, 32, 64);
  uint32_t x1 = (uint32_t)__shfl_xor((int)p1, 32, 64);
  uint32_t x2 = (uint32_t)__shfl_xor((int)p2, 32, 64);
  uint32_t x3 = (uint32_t)__shfl_xor((int)p3, 32, 64);
  u32x4 v;
  v[0] = hi ? x2 : p0;
  v[1] = hi ? x3 : p1;
  v[2] = hi ? p2 : x0;
  v[3] = hi ? p3 : x1;
  return __builtin_bit_cast(bf16x8, v);
}

__global__ __launch_bounds__(256, 2) void attn_kernel(
    const uint16_t* __restrict__ Qb, const uint16_t* __restrict__ Kb,
    const uint16_t* __restrict__ Vt, uint16_t* __restrict__ zb,
    const float* __restrict__ cosT, const float* __restrict__ sinT) {
  __shared__ uint16_t Ksh[2][64 * 128];   // [kv 64][d 128], 16B-chunk xor-swizzled by (kv&7)
  __shared__ uint16_t Vsh[2][128 * 64];   // [d 128][kv 64], 16B-chunk xor-swizzled by (d&7)

  const int t = threadIdx.x, lane = t & 63, w = t >> 6;
  const int l31 = lane & 31, hi = lane >> 5;
  const int bx = blockIdx.x, bh = blockIdx.y;
  const int qt = (bh & 16) ? (15 - bx) : bx;   // CU-pair balance: qt + qt' = 15
  const int q0 = qt * 128;
  const int qg = q0 + w * 32 + l31;
  const size_t hbase = (size_t)bh * 2048 * 128;

#define ATT_STAGE(kt, buf)                                                        \
  do {                                                                            \
    const uint16_t* Kg_ = Kb + hbase + (size_t)(kt) * 64 * 128;                   \
    const uint16_t* Vg_ = Vt + hbase + (size_t)(kt) * 64;                         \
    _Pragma("unroll")                                                             \
    for (int i_ = 0; i_ < 4; i_++) {                                              \
      int c_ = t + i_ * 256;                                                      \
      { int row_ = c_ >> 4, cc_ = c_ & 15, scc_ = cc_ ^ (row_ & 7);               \
        gll16(&Kg_[row_ * 128 + scc_ * 8], &Ksh[buf][(c_ & ~63) * 8]); }          \
      { int r_ = c_ >> 3, cc_ = c_ & 7, scc_ = cc_ ^ (r_ & 7);                    \
        gll16(&Vg_[(size_t)r_ * 2048 + scc_ * 8], &Vsh[buf][(c_ & ~63) * 8]); }   \
    }                                                                             \
  } while (0)

  // ---- load Q frags and apply RoPE in-register (Q already carries QSCALE)
  bf16x8 qf[8];
#pragma unroll
  for (int dc = 0; dc < 8; ++dc)
    qf[dc] = *(const bf16x8*)&Qb[hbase + (size_t)qg * 128 + dc * 16 + hi * 8];
#pragma unroll
  for (int dc = 0; dc < 4; ++dc) {
    int d0 = dc * 16 + hi * 8;
    float4 c0 = *(const float4*)&cosT[(qg << 6) + d0];
    float4 c1 = *(const float4*)&cosT[(qg << 6) + d0 + 4];
    float4 n0 = *(const float4*)&sinT[(qg << 6) + d0];
    float4 n1 = *(const float4*)&sinT[(qg << 6) + d0 + 4];
    float cs[8] = {c0.x, c0.y, c0.z, c0.w, c1.x, c1.y, c1.z, c1.w};
    float sn[8] = {n0.x, n0.y, n0.z, n0.w, n1.x, n1.y, n1.z, n1.w};
    uint32_t lo2[4], hi2[4];
#pragma unroll
    for (int j = 0; j < 4; ++j) {
      float xl0 = bf2f((uint16_t)qf[dc][2 * j]),     xh0 = bf2f((uint16_t)qf[dc + 4][2 * j]);
      float xl1 = bf2f((uint16_t)qf[dc][2 * j + 1]), xh1 = bf2f((uint16_t)qf[dc + 4][2 * j + 1]);
      lo2[j] = cvtpk(xl0 * cs[2 * j] - xh0 * sn[2 * j], xl1 * cs[2 * j + 1] - xh1 * sn[2 * j + 1]);
      hi2[j] = cvtpk(xh0 * cs[2 * j] + xl0 * sn[2 * j], xh1 * cs[2 * j + 1] + xl1 * sn[2 * j + 1]);
    }
    { u32x4 v = {lo2[0], lo2[1], lo2[2], lo2[3]}; qf[dc]     = __builtin_bit_cast(bf16x8, v); }
    { u32x4 v = {hi2[0], hi2[1], hi2[2], hi2[3]}; qf[dc + 4] = __builtin_bit_cast(bf16x8, v); }
  }

  f32x16 oacc[4];
#pragma unroll
  for (int i = 0; i < 4; i++) oacc[i] = (f32x16)(0.0f);
  float mrow = -1e30f, lrow = 0.0f;

  const int ktiles = 2 * qt + 2;
  ATT_STAGE(0, 0);
  asm volatile("s_waitcnt vmcnt(0)" ::: "memory");
  BARRIER();

  for (int kt = 0; kt < ktiles; ++kt) {
    const int cur = kt & 1;
    if (kt + 1 < ktiles) ATT_STAGE(kt + 1, cur ^ 1);

    const int kv_base = kt * 64;
    if (kv_base <= q0 + w * 32 + 31) {
      f32x16 s0 = (f32x16)(0.0f), s1 = (f32x16)(0.0f);
      __builtin_amdgcn_s_setprio(1);
#pragma unroll
      for (int dc = 0; dc < 8; ++dc) {
        int ch = dc * 2 + hi;
        bf16x8 k0 = *(const bf16x8*)&Ksh[cur][l31 * 128 + ((ch ^ (l31 & 7)) * 8)];
        bf16x8 k1 = *(const bf16x8*)&Ksh[cur][(32 + l31) * 128 + ((ch ^ (l31 & 7)) * 8)];
        s0 = __builtin_amdgcn_mfma_f32_32x32x16_bf16(k0, qf[dc], s0, 0, 0, 0);
        s1 = __builtin_amdgcn_mfma_f32_32x32x16_bf16(k1, qf[dc], s1, 0, 0, 0);
      }
      __builtin_amdgcn_s_setprio(0);

      // mask in place only on diagonal tiles (Q already carries scale*log2e)
      if (kv_base + 63 > q0 + w * 32) {
#pragma unroll
        for (int reg = 0; reg < 16; ++reg) {
          int koff = (reg & 3) + 8 * (reg >> 2) + 4 * hi;
          if (kv_base + koff > qg) s0[reg] = -1e30f;
          if (kv_base + 32 + koff > qg) s1[reg] = -1e30f;
        }
      }

      // ---- row max: tree
      float m8[8];
#pragma unroll
      for (int i = 0; i < 8; ++i)
        m8[i] = fmaxf(fmaxf(s0[i], s0[i + 8]), fmaxf(s1[i], s1[i + 8]));
      float pmax = fmaxf(fmaxf(fmaxf(m8[0], m8[4]), fmaxf(m8[1], m8[5])),
                         fmaxf(fmaxf(m8[2], m8[6]), fmaxf(m8[3], m8[7])));
      pmax = fmaxf(pmax, __shfl_xor(pmax, 32, 64));

      bool defer = __all(pmax <= mrow + 8.0f);
      if (!defer) {
        float mnew = fmaxf(mrow, pmax);
        float al = exp2f(mrow - mnew);
        lrow *= al;
#pragma unroll
        for (int reg = 0; reg < 16; ++reg) {
          int src = (reg & 3) + 8 * (reg >> 2) + 4 * hi;
          float ar = __shfl(al, src, 64);
#pragma unroll
          for (int n = 0; n < 4; ++n) oacc[n][reg] *= ar;
        }
        mrow = mnew;
      }

      // ---- P = exp2(s - mrow): cvt_pk pack + 4-way partial sums
      float ps0 = 0.0f, ps1 = 0.0f, ps2 = 0.0f, ps3 = 0.0f;
      uint32_t pk0[8], pk1[8];
#pragma unroll
      for (int i = 0; i < 8; ++i) {
        float a = exp2f(s0[2 * i] - mrow), b = exp2f(s0[2 * i + 1] - mrow);
        ps0 += a; ps1 += b;
        pk0[i] = cvtpk(a, b);
        float c = exp2f(s1[2 * i] - mrow), d = exp2f(s1[2 * i + 1] - mrow);
        ps2 += c; ps3 += d;
        pk1[i] = cvtpk(c, d);
      }
      float ps = (ps0 + ps1) + (ps2 + ps3);
      ps += __shfl_xor(ps, 32, 64);
      lrow += ps;

      bf16x8 pa[4];
      pa[0] = mk_pa(pk0[0], pk0[1], pk0[2], pk0[3], hi);
      pa[1] = mk_pa(pk0[4], pk0[5], pk0[6], pk0[7], hi);
      pa[2] = mk_pa(pk1[0], pk1[1], pk1[2], pk1[3], hi);
      pa[3] = mk_pa(pk1[4], pk1[5], pk1[6], pk1[7], hi);

      __builtin_amdgcn_s_setprio(1);
#pragma unroll
      for (int ksl = 0; ksl < 4; ++ksl) {
        int ch = ksl * 2 + hi;
#pragma unroll
        for (int n = 0; n < 4; ++n) {
          int d = n * 32 + l31;
          bf16x8 vf = *(const bf16x8*)&Vsh[cur][d * 64 + ((ch ^ (d & 7)) * 8)];
          oacc[n] = __builtin_amdgcn_mfma_f32_32x32x16_bf16(pa[ksl], vf, oacc[n], 0, 0, 0);
        }
      }
      __builtin_amdgcn_s_setprio(0);
    }

    if (kt + 1 < ktiles) {
      asm volatile("s_waitcnt vmcnt(0)" ::: "memory");  // next tile staged
      BARRIER();
    }
  }
#undef ATT_STAGE

  const int b = bh >> 4, h = bh & 15;
  const float linv_own = 1.0f / lrow;   // one divide per lane (its own q-row)
#pragma unroll
  for (int reg = 0; reg < 16; ++reg) {
    int rloc = (reg & 3) + 8 * (reg >> 2) + 4 * hi;
    float linv = __shfl(linv_own, rloc, 64);
    int rowg = q0 + w * 32 + rloc;
    size_t base = ((size_t)b * 2048 + rowg) * 2048 + h * 128 + l31;
#pragma unroll
    for (int n = 0; n < 4; ++n)
      zb[base + n * 32] = f2bf(oacc[n][reg] * linv);
  }
}

// ---------------------------------------------------------------- launch
extern "C" void kernel_launch(void* const* d_in, const int* in_sizes, int n_in,
                              void* d_out, int out_size, void* d_ws, size_t ws_size,
                              hipStream_t stream) {
  const float* x    = (const float*)d_in[0];
  const float* Wqkv = (const float*)d_in[1];
  const float* Wo   = (const float*)d_in[2];
  float* out = (float*)d_out;
  char* ws = (char*)d_ws;

  uint16_t* Qb    = (uint16_t*)(ws + 0);            // 16 MB
  uint16_t* Kb    = (uint16_t*)(ws + 16777216);     // 16 MB
  uint16_t* Vt    = (uint16_t*)(ws + 33554432);     // 16 MB  [b,h,128,2048]
  uint16_t* xb    = (uint16_t*)(ws + 50331648);     // 16 MB (dead after gemm_qkv)
  uint16_t* zb    = (uint16_t*)(ws + 50331648);     // alias xb
  uint16_t* wqkvb = (uint16_t*)(ws + 67108864);     // 24 MB
  uint16_t* wob   = (uint16_t*)(ws + 92274688);     //  8 MB
  float*    cosT  = (float*)   (ws + 100663296);
  float*    sinT  = (float*)   (ws + 101187584);

  cvt_all<<<12800, 256, 0, stream>>>(x, Wqkv, Wo, xb, wqkvb, wob, cosT, sinT);

  gemm_qkv<<<dim3(16, 32), 512, 114688, stream>>>(xb, wqkvb, Qb, Kb, Vt);

  rope_apply_k<<<4096, 256, 0, stream>>>(Kb, cosT, sinT);

  attn_kernel<<<dim3(16, 32), 256, 0, stream>>>(Qb, Kb, Vt, zb, cosT, sinT);

  gemm_out_k<<<dim3(16, 16), 512, 98304, stream>>>(zb, wob, out);
}